// Round 6
// baseline (928.587 us; speedup 1.0000x reference)
//
#include <hip/hip_runtime.h>
#include <float.h>

#define BATCH 8
#define SEQ   1024
#define CDIM  512
#define HEADS 8
#define HD    64
#define TOPK  16
#define MTOT  (BATCH*SEQ)                     // 8192
#define HSZ   ((size_t)BATCH*HEADS*SEQ*HD)    // 4194304
#define XPLANE  ((size_t)MTOT*CDIM)           // 4194304
#define WTPLANE ((size_t)3*CDIM*CDIM)         // 786432  (1536x512)
#define WPPLANE ((size_t)CDIM*CDIM)           // 262144  (512x512)

typedef short bf16x8 __attribute__((ext_vector_type(8)));
typedef float f32x4v __attribute__((ext_vector_type(4)));
typedef unsigned short u16;

#define MFMA16(a,b,c) __builtin_amdgcn_mfma_f32_16x16x32_bf16((a),(b),(c),0,0,0)

// round-to-nearest bf16 split: f = hi + lo, each bf16; |err| ~ 2^-17 |f|
__device__ inline void bf16split(float f, u16& h, u16& l) {
    unsigned u = __float_as_uint(f);
    unsigned hr = (u + 0x7fffu + ((u >> 16) & 1u)) >> 16;
    h = (u16)hr;
    float rest = f - __uint_as_float(hr << 16);
    unsigned v = __float_as_uint(rest);
    l = (u16)((v + 0x7fffu + ((v >> 16) & 1u)) >> 16);
}

__device__ inline void bf16split4(float4 f, ushort4& h, ushort4& l) {
    bf16split(f.x, h.x, l.x); bf16split(f.y, h.y, l.y);
    bf16split(f.z, h.z, l.z); bf16split(f.w, h.w, l.w);
}

// ============================================================
// Prep 1: elementwise split fp32 -> bf16 hi/lo planes
// ============================================================
__global__ __launch_bounds__(256) void split_f32_kernel(
    const float* __restrict__ in, u16* __restrict__ hi, u16* __restrict__ lo, int n4)
{
    int i = blockIdx.x * 256 + threadIdx.x;
    if (i < n4) {
        float4 f = ((const float4*)in)[i];
        ushort4 h, l; bf16split4(f, h, l);
        ((ushort4*)hi)[i] = h; ((ushort4*)lo)[i] = l;
    }
}

// ============================================================
// Prep 2: transpose + split.  W:[512][ncols] fp32 -> out:[ncols][512] hi/lo
// ============================================================
__global__ __launch_bounds__(256) void tsplit_kernel(
    const float* __restrict__ W, int ncols, u16* __restrict__ ohi, u16* __restrict__ olo)
{
    __shared__ float t_s[64][65];
    const int tid = threadIdx.x, tx = tid & 15, ty = tid >> 4;
    const int cb = blockIdx.x * 64, kb = blockIdx.y * 64;
    #pragma unroll
    for (int i = 0; i < 4; i++)
        *(float4*)&t_s[ty*4+i][tx*4] =
            *(const float4*)(W + (size_t)(kb + ty*4 + i) * ncols + cb + tx*4);
    __syncthreads();
    #pragma unroll
    for (int i = 0; i < 4; i++) {
        int rr = ty*4 + i;
        float4 f;
        f.x = t_s[tx*4+0][rr]; f.y = t_s[tx*4+1][rr];
        f.z = t_s[tx*4+2][rr]; f.w = t_s[tx*4+3][rr];
        ushort4 h, l; bf16split4(f, h, l);
        *(ushort4*)(ohi + (size_t)(cb + rr) * 512 + kb + tx*4) = h;
        *(ushort4*)(olo + (size_t)(cb + rr) * 512 + kb + tx*4) = l;
    }
}

// ============================================================
// Kernel 1: QKV projection, split-bf16 MFMA.
// Epilogue: bias; q: relu then *0.125 (exact pow2 — pre-scales scores);
// q,k -> bf16 hi/lo planes, v fp32.
// ============================================================
__global__ __launch_bounds__(256) void qkv_mfma_kernel(
    const u16* __restrict__ xpl,      // [2][8192][512]
    const u16* __restrict__ wtpl,     // [2][1536][512]
    const float* __restrict__ bq, const float* __restrict__ bkv,
    u16* __restrict__ qhi_g, u16* __restrict__ qlo_g,
    u16* __restrict__ khi_g, u16* __restrict__ klo_g,
    float* __restrict__ v_ws)
{
    __shared__ __align__(16) char smem[32768];
    u16*   a_s = (u16*)smem;              // [2][4096] shorts
    u16*   b_s = (u16*)(smem + 16384);    // [2][4096] shorts
    float* e_s = (float*)smem;            // epilogue overlay [32][132]

    const int tid = threadIdx.x, lane = tid & 63, w = tid >> 6;
    const int row0 = blockIdx.x * 128;
    const int by = blockIdx.y;            // 0..11: 0-3 q, 4-7 k, 8-11 v
    const int c0 = by * 128;

    f32x4v acc[2][8];
    #pragma unroll
    for (int rt = 0; rt < 2; rt++)
        #pragma unroll
        for (int nt = 0; nt < 8; nt++) acc[rt][nt] = (f32x4v){0.f,0.f,0.f,0.f};

    int gpl[4], goff_a[4], goff_b[4], glds[4];
    #pragma unroll
    for (int i = 0; i < 4; i++) {
        int gid = tid * 4 + i;
        int pl = gid >> 9, rem = gid & 511;
        int rt = rem >> 6, l = rem & 63;
        gpl[i]    = pl;
        goff_a[i] = (row0 + rt*16 + (l & 15)) * 512 + ((l >> 4) * 8);
        goff_b[i] = (c0   + rt*16 + (l & 15)) * 512 + ((l >> 4) * 8);
        glds[i]   = pl * 4096 + (rt*64 + l) * 8;
    }

    uint4 ar[4], br[4];
    #pragma unroll
    for (int i = 0; i < 4; i++) {
        ar[i] = *(const uint4*)(xpl  + (size_t)gpl[i]*XPLANE  + goff_a[i]);
        br[i] = *(const uint4*)(wtpl + (size_t)gpl[i]*WTPLANE + goff_b[i]);
    }

    for (int kc = 0; kc < 16; kc++) {
        __syncthreads();
        #pragma unroll
        for (int i = 0; i < 4; i++) {
            *(uint4*)&a_s[glds[i]] = ar[i];
            *(uint4*)&b_s[glds[i]] = br[i];
        }
        __syncthreads();
        if (kc < 15) {
            int ko = (kc + 1) * 32;
            #pragma unroll
            for (int i = 0; i < 4; i++) {
                ar[i] = *(const uint4*)(xpl  + (size_t)gpl[i]*XPLANE  + goff_a[i] + ko);
                br[i] = *(const uint4*)(wtpl + (size_t)gpl[i]*WTPLANE + goff_b[i] + ko);
            }
        }
        bf16x8 a0h = *(bf16x8*)&a_s[(((2*w+0)*64) + lane) * 8];
        bf16x8 a0l = *(bf16x8*)&a_s[4096 + (((2*w+0)*64) + lane) * 8];
        bf16x8 a1h = *(bf16x8*)&a_s[(((2*w+1)*64) + lane) * 8];
        bf16x8 a1l = *(bf16x8*)&a_s[4096 + (((2*w+1)*64) + lane) * 8];
        #pragma unroll
        for (int nt = 0; nt < 8; nt++) {
            bf16x8 bh_ = *(bf16x8*)&b_s[(nt*64 + lane) * 8];
            bf16x8 bl_ = *(bf16x8*)&b_s[4096 + (nt*64 + lane) * 8];
            acc[0][nt] = MFMA16(a0h, bh_, acc[0][nt]);
            acc[0][nt] = MFMA16(a0h, bl_, acc[0][nt]);
            acc[0][nt] = MFMA16(a0l, bh_, acc[0][nt]);
            acc[1][nt] = MFMA16(a1h, bh_, acc[1][nt]);
            acc[1][nt] = MFMA16(a1h, bl_, acc[1][nt]);
            acc[1][nt] = MFMA16(a1l, bh_, acc[1][nt]);
        }
    }

    for (int p = 0; p < 4; p++) {
        __syncthreads();
        if (w == p) {
            #pragma unroll
            for (int rt = 0; rt < 2; rt++)
                #pragma unroll
                for (int nt = 0; nt < 8; nt++) {
                    int rl = rt*16 + (lane >> 4) * 4;
                    int cl = nt*16 + (lane & 15);
                    #pragma unroll
                    for (int rg = 0; rg < 4; rg++)
                        e_s[(rl + rg) * 132 + cl] = acc[rt][nt][rg];
                }
        }
        __syncthreads();
        int rl = tid >> 3;                // 0..31
        int cb = (tid & 7) * 16;
        int rg = row0 + p*32 + rl;
        int bb = rg >> 10, nn = rg & (SEQ - 1);
        #pragma unroll
        for (int j4 = 0; j4 < 4; j4++) {
            float4 f = *(float4*)&e_s[rl * 132 + cb + j4*4];
            int cg = c0 + cb + j4*4;      // 0..1535
            if (by < 4) {
                float4 bias = *(const float4*)(bq + cg);
                f.x = fmaxf(f.x + bias.x, 0.f) * 0.125f;
                f.y = fmaxf(f.y + bias.y, 0.f) * 0.125f;
                f.z = fmaxf(f.z + bias.z, 0.f) * 0.125f;
                f.w = fmaxf(f.w + bias.w, 0.f) * 0.125f;
                int h = cg >> 6, d = cg & 63;
                size_t base = (((size_t)bb*HEADS + h)*SEQ + nn)*HD + d;
                ushort4 hv, lv; bf16split4(f, hv, lv);
                *(ushort4*)(qhi_g + base) = hv;
                *(ushort4*)(qlo_g + base) = lv;
            } else {
                int c2 = cg - CDIM;       // 0..1023
                float4 bias = *(const float4*)(bkv + c2);
                f.x += bias.x; f.y += bias.y; f.z += bias.z; f.w += bias.w;
                if (by < 8) {             // k
                    int h = c2 >> 6, d = c2 & 63;
                    size_t base = (((size_t)bb*HEADS + h)*SEQ + nn)*HD + d;
                    ushort4 hv, lv; bf16split4(f, hv, lv);
                    *(ushort4*)(khi_g + base) = hv;
                    *(ushort4*)(klo_g + base) = lv;
                } else {                  // v
                    int c3 = c2 - CDIM; int h = c3 >> 6, d = c3 & 63;
                    size_t base = (((size_t)bb*HEADS + h)*SEQ + nn)*HD + d;
                    *(float4*)(v_ws + base) = f;
                }
            }
        }
    }
}

// ============================================================
// Kernel 2: per-(b,h) column sum of V  -> vsum[bh][64]
// ============================================================
__global__ __launch_bounds__(256) void vsum_kernel(
    const float* __restrict__ v_ws, float* __restrict__ vsum_ws)
{
    __shared__ float red[4][HD];
    const int bh = blockIdx.x;
    const int d  = threadIdx.x & 63;
    const int sl = threadIdx.x >> 6;
    const float* vh = v_ws + (size_t)bh * SEQ * HD;
    float s = 0.f;
    for (int m = sl * 256; m < (sl + 1) * 256; m++) s += vh[(size_t)m * HD + d];
    red[sl][d] = s;
    __syncthreads();
    if (threadIdx.x < HD)
        vsum_ws[(size_t)bh * HD + d] = red[0][d] + red[1][d] + red[2][d] + red[3][d];
}

// ============================================================
// Kernel 3: BARRIER-FREE fused scores + top-16 + softmax + PV.
// Zero LDS. One wave owns 16 query rows. Q/K fragments loaded directly
// from the global hi/lo planes (fragment-contiguous 16B per lane).
// Per K-tile: 6 MFMA, store acc as ONE dwordx4 into a wave-private
// 64KB blob (C-layout). Then s_waitcnt(0) (per-wave, no barrier) and
// read back own blob (L2-hot) for 16-round wave-argmax extraction
// (exact jax tie order: value desc, col asc), softmax, PV.
// Blob map: blob[T][lane][rg], col = j*64 + l for readback lane l iter j.
// ============================================================
__global__ __launch_bounds__(256) void attn_kernel(
    const u16* __restrict__ qhi_g, const u16* __restrict__ qlo_g,
    const u16* __restrict__ khi_g, const u16* __restrict__ klo_g,
    const float* __restrict__ v_ws, const float* __restrict__ vsum_ws,
    float* __restrict__ s_g, int bh0,
    u16* __restrict__ aohi, u16* __restrict__ aolo)
{
    const int bhl = blockIdx.y, bh = bh0 + bhl;
    const int tid = threadIdx.x, lane = tid & 63, w = tid >> 6;
    const int n0 = blockIdx.x * 64 + w * 16;      // this wave's first row
    const size_t hb = (size_t)bh * SEQ * HD;
    const int l15 = lane & 15, l4 = lane >> 4;

    // Q fragments direct from global: A[m = n0+l15][k = l4*8 + h*32]
    bf16x8 qh[2], ql[2];
    {
        const size_t qoff = hb + (size_t)(n0 + l15) * HD + l4 * 8;
        qh[0] = *(const bf16x8*)(qhi_g + qoff);
        qh[1] = *(const bf16x8*)(qhi_g + qoff + 32);
        ql[0] = *(const bf16x8*)(qlo_g + qoff);
        ql[1] = *(const bf16x8*)(qlo_g + qoff + 32);
    }

    float* sb = s_g + (((size_t)bhl * 16 + blockIdx.x) * 4 + w) * 16384;

    // scores: 64 K-tiles of 16 cols, no barriers
    #pragma unroll 2
    for (int T = 0; T < 64; T++) {
        const size_t koff = hb + (size_t)(T * 16 + l15) * HD + l4 * 8;
        bf16x8 kh0 = *(const bf16x8*)(khi_g + koff);
        bf16x8 kh1 = *(const bf16x8*)(khi_g + koff + 32);
        bf16x8 kl0 = *(const bf16x8*)(klo_g + koff);
        bf16x8 kl1 = *(const bf16x8*)(klo_g + koff + 32);
        f32x4v acc = {0.f, 0.f, 0.f, 0.f};
        acc = MFMA16(qh[0], kh0, acc);
        acc = MFMA16(qh[0], kl0, acc);
        acc = MFMA16(ql[0], kh0, acc);
        acc = MFMA16(qh[1], kh1, acc);
        acc = MFMA16(qh[1], kl1, acc);
        acc = MFMA16(ql[1], kh1, acc);
        float4 st; st.x = acc[0]; st.y = acc[1]; st.z = acc[2]; st.w = acc[3];
        *(float4*)(sb + (T * 64 + lane) * 4) = st;   // blob[T][lane][0..3]
    }

    __builtin_amdgcn_s_waitcnt(0);   // own stores visible to own loads

    // extraction + softmax + PV for this wave's 16 rows
    const float* vh = v_ws + ((size_t)bh << 16);
    const float vs = vsum_ws[(bh << 6) + lane];
    const int lbase = l4 * 256 + l15 * 4;
    #pragma unroll 1
    for (int rr = 0; rr < 16; rr++) {
        const int n = n0 + rr;
        const float* rb = sb + lbase + (rr >> 2) * 64 + (rr & 3);
        float v[16];
        #pragma unroll
        for (int j = 0; j < 16; j++) v[j] = rb[j * 1024];   // col = j*64+lane
        float mv[TOPK]; int mi[TOPK];
        #pragma unroll
        for (int t = 0; t < TOPK; t++) {
            float bv = v[0]; int bj = 0;
            #pragma unroll
            for (int j = 1; j < 16; j++) { if (v[j] > bv) { bv = v[j]; bj = j; } }
            int bc = bj * 64 + lane;
            #pragma unroll
            for (int off = 32; off; off >>= 1) {
                float ov = __shfl_xor(bv, off);
                int   oc = __shfl_xor(bc, off);
                if (ov > bv || (ov == bv && oc < bc)) { bv = ov; bc = oc; }
            }
            mv[t] = bv; mi[t] = bc;
            int jj = ((bc & 63) == lane) ? (bc >> 6) : -1;
            #pragma unroll
            for (int j = 0; j < 16; j++) { if (j == jj) v[j] = -FLT_MAX; }
        }
        float mx = fmaxf(mv[0], 0.f);
        float e  = expf(-mx);
        float Z  = (float)(SEQ - TOPK) * e;
        float wexp[TOPK];
        #pragma unroll
        for (int t = 0; t < TOPK; t++) { wexp[t] = expf(mv[t] - mx); Z += wexp[t]; }
        float invZ = 1.f / Z;
        float acc = (e * invZ) * vs;
        #pragma unroll
        for (int t = 0; t < TOPK; t++)
            acc = fmaf((wexp[t] - e) * invZ, vh[((size_t)mi[t] << 6) + lane], acc);
        u16 oh, ol; bf16split(acc, oh, ol);
        size_t oidx = (((size_t)(bh >> 3) << 10) + n) * CDIM + ((bh & 7) << 6) + lane;
        aohi[oidx] = oh; aolo[oidx] = ol;
    }
}

// ============================================================
// Kernel 4: output projection, split-bf16 MFMA.  out = ao @ Wp + bp
// ============================================================
__global__ __launch_bounds__(256) void proj_mfma_kernel(
    const u16* __restrict__ apl,      // [2][8192][512]
    const u16* __restrict__ wppl,     // [2][512][512]
    const float* __restrict__ bp, float* __restrict__ out)
{
    __shared__ __align__(16) char smem[32768];
    u16*   a_s = (u16*)smem;
    u16*   b_s = (u16*)(smem + 16384);
    float* e_s = (float*)smem;

    const int tid = threadIdx.x, lane = tid & 63, w = tid >> 6;
    const int row0 = blockIdx.x * 128;
    const int c0 = blockIdx.y * 128;

    f32x4v acc[2][8];
    #pragma unroll
    for (int rt = 0; rt < 2; rt++)
        #pragma unroll
        for (int nt = 0; nt < 8; nt++) acc[rt][nt] = (f32x4v){0.f,0.f,0.f,0.f};

    int gpl[4], goff_a[4], goff_b[4], glds[4];
    #pragma unroll
    for (int i = 0; i < 4; i++) {
        int gid = tid * 4 + i;
        int pl = gid >> 9, rem = gid & 511;
        int rt = rem >> 6, l = rem & 63;
        gpl[i]    = pl;
        goff_a[i] = (row0 + rt*16 + (l & 15)) * 512 + ((l >> 4) * 8);
        goff_b[i] = (c0   + rt*16 + (l & 15)) * 512 + ((l >> 4) * 8);
        glds[i]   = pl * 4096 + (rt*64 + l) * 8;
    }

    uint4 ar[4], br[4];
    #pragma unroll
    for (int i = 0; i < 4; i++) {
        ar[i] = *(const uint4*)(apl  + (size_t)gpl[i]*XPLANE  + goff_a[i]);
        br[i] = *(const uint4*)(wppl + (size_t)gpl[i]*WPPLANE + goff_b[i]);
    }

    for (int kc = 0; kc < 16; kc++) {
        __syncthreads();
        #pragma unroll
        for (int i = 0; i < 4; i++) {
            *(uint4*)&a_s[glds[i]] = ar[i];
            *(uint4*)&b_s[glds[i]] = br[i];
        }
        __syncthreads();
        if (kc < 15) {
            int ko = (kc + 1) * 32;
            #pragma unroll
            for (int i = 0; i < 4; i++) {
                ar[i] = *(const uint4*)(apl  + (size_t)gpl[i]*XPLANE  + goff_a[i] + ko);
                br[i] = *(const uint4*)(wppl + (size_t)gpl[i]*WPPLANE + goff_b[i] + ko);
            }
        }
        bf16x8 a0h = *(bf16x8*)&a_s[(((2*w+0)*64) + lane) * 8];
        bf16x8 a0l = *(bf16x8*)&a_s[4096 + (((2*w+0)*64) + lane) * 8];
        bf16x8 a1h = *(bf16x8*)&a_s[(((2*w+1)*64) + lane) * 8];
        bf16x8 a1l = *(bf16x8*)&a_s[4096 + (((2*w+1)*64) + lane) * 8];
        #pragma unroll
        for (int nt = 0; nt < 8; nt++) {
            bf16x8 bh_ = *(bf16x8*)&b_s[(nt*64 + lane) * 8];
            bf16x8 bl_ = *(bf16x8*)&b_s[4096 + (nt*64 + lane) * 8];
            acc[0][nt] = MFMA16(a0h, bh_, acc[0][nt]);
            acc[0][nt] = MFMA16(a0h, bl_, acc[0][nt]);
            acc[0][nt] = MFMA16(a0l, bh_, acc[0][nt]);
            acc[1][nt] = MFMA16(a1h, bh_, acc[1][nt]);
            acc[1][nt] = MFMA16(a1h, bl_, acc[1][nt]);
            acc[1][nt] = MFMA16(a1l, bh_, acc[1][nt]);
        }
    }

    for (int p = 0; p < 4; p++) {
        __syncthreads();
        if (w == p) {
            #pragma unroll
            for (int rt = 0; rt < 2; rt++)
                #pragma unroll
                for (int nt = 0; nt < 8; nt++) {
                    int rl = rt*16 + (lane >> 4) * 4;
                    int cl = nt*16 + (lane & 15);
                    #pragma unroll
                    for (int rg = 0; rg < 4; rg++)
                        e_s[(rl + rg) * 132 + cl] = acc[rt][nt][rg];
                }
        }
        __syncthreads();
        int rl = tid >> 3;
        int cb = (tid & 7) * 16;
        int rg = row0 + p*32 + rl;
        #pragma unroll
        for (int j4 = 0; j4 < 4; j4++) {
            float4 f = *(float4*)&e_s[rl * 132 + cb + j4*4];
            int cg = c0 + cb + j4*4;
            float4 bias = *(const float4*)(bp + cg);
            f.x += bias.x; f.y += bias.y; f.z += bias.z; f.w += bias.w;
            *(float4*)(out + (size_t)rg * CDIM + cg) = f;
        }
    }
}

// ============================================================
extern "C" void kernel_launch(void* const* d_in, const int* in_sizes, int n_in,
                              void* d_out, int out_size, void* d_ws, size_t ws_size,
                              hipStream_t stream)
{
    const float* x   = (const float*)d_in[0];
    const float* Wq  = (const float*)d_in[1];
    const float* bq  = (const float*)d_in[2];
    const float* Wkv = (const float*)d_in[3];
    const float* bkv = (const float*)d_in[4];
    const float* Wp  = (const float*)d_in[5];
    const float* bp  = (const float*)d_in[6];
    float* out = (float*)d_out;

    // workspace layout
    float* ws    = (float*)d_ws;
    float* v_ws  = ws;                               // HSZ fl
    float* vs_ws = v_ws + HSZ;                       // 4096 fl
    u16* qhi_g = (u16*)(vs_ws + 4096);
    u16* qlo_g = qhi_g + HSZ;
    u16* khi_g = qhi_g + 2 * HSZ;
    u16* klo_g = qhi_g + 3 * HSZ;
    u16* xpl   = qhi_g + 4 * HSZ;                    // 2 planes
    u16* wtpl  = xpl + 2 * XPLANE;                   // 2 planes
    u16* wppl  = wtpl + 2 * WTPLANE;                 // 2 planes
    u16* aohi  = wppl + 2 * WPPLANE;
    u16* aolo  = aohi + XPLANE;
    float* s_g = (float*)(aolo + XPLANE);

    const size_t base_fl  = (size_t)(s_g - ws);
    const size_t avail_fl = (ws_size / 4 > base_fl) ? (ws_size / 4 - base_fl) : 0;
    int G = 64;
    while (G > 1 && (size_t)G * SEQ * SEQ > avail_fl) G >>= 1;

    split_f32_kernel<<<(int)((XPLANE/4 + 255)/256), 256, 0, stream>>>(
        x, xpl, xpl + XPLANE, (int)(XPLANE/4));
    tsplit_kernel<<<dim3(8, 8),  256, 0, stream>>>(Wq,  512,  wtpl, wtpl + WTPLANE);
    tsplit_kernel<<<dim3(16, 8), 256, 0, stream>>>(Wkv, 1024, wtpl + (size_t)512*512,
                                                   wtpl + WTPLANE + (size_t)512*512);
    tsplit_kernel<<<dim3(8, 8),  256, 0, stream>>>(Wp,  512,  wppl, wppl + WPPLANE);

    qkv_mfma_kernel<<<dim3(64, 12), 256, 0, stream>>>(
        xpl, wtpl, bq, bkv, qhi_g, qlo_g, khi_g, klo_g, v_ws);
    vsum_kernel<<<BATCH * HEADS, 256, 0, stream>>>(v_ws, vs_ws);
    for (int bh0 = 0; bh0 < BATCH * HEADS; bh0 += G) {
        attn_kernel<<<dim3(SEQ / 64, G), 256, 0, stream>>>(
            qhi_g, qlo_g, khi_g, klo_g, v_ws, vs_ws, s_g, bh0, aohi, aolo);
    }
    proj_mfma_kernel<<<dim3(64, 4), 256, 0, stream>>>(aohi, wppl, bp, out);
}

// Round 7
// 641.538 us; speedup vs baseline: 1.4474x; 1.4474x over previous
//
#include <hip/hip_runtime.h>
#include <float.h>

#define BATCH 8
#define SEQ   1024
#define CDIM  512
#define HEADS 8
#define HD    64
#define TOPK  16
#define MTOT  (BATCH*SEQ)                     // 8192
#define HSZ   ((size_t)BATCH*HEADS*SEQ*HD)    // 4194304
#define XPLANE  ((size_t)MTOT*CDIM)           // 4194304
#define WTPLANE ((size_t)3*CDIM*CDIM)         // 786432  (1536x512)
#define WPPLANE ((size_t)CDIM*CDIM)           // 262144  (512x512)

typedef short bf16x8 __attribute__((ext_vector_type(8)));
typedef float f32x4v __attribute__((ext_vector_type(4)));
typedef unsigned short u16;

#define MFMA16(a,b,c) __builtin_amdgcn_mfma_f32_16x16x32_bf16((a),(b),(c),0,0,0)

// round-to-nearest bf16 split: f = hi + lo, each bf16; |err| ~ 2^-17 |f|
__device__ inline void bf16split(float f, u16& h, u16& l) {
    unsigned u = __float_as_uint(f);
    unsigned hr = (u + 0x7fffu + ((u >> 16) & 1u)) >> 16;
    h = (u16)hr;
    float rest = f - __uint_as_float(hr << 16);
    unsigned v = __float_as_uint(rest);
    l = (u16)((v + 0x7fffu + ((v >> 16) & 1u)) >> 16);
}

__device__ inline void bf16split4(float4 f, ushort4& h, ushort4& l) {
    bf16split(f.x, h.x, l.x); bf16split(f.y, h.y, l.y);
    bf16split(f.z, h.z, l.z); bf16split(f.w, h.w, l.w);
}

// ============================================================
// Prep 1: elementwise split fp32 -> bf16 hi/lo planes
// ============================================================
__global__ __launch_bounds__(256) void split_f32_kernel(
    const float* __restrict__ in, u16* __restrict__ hi, u16* __restrict__ lo, int n4)
{
    int i = blockIdx.x * 256 + threadIdx.x;
    if (i < n4) {
        float4 f = ((const float4*)in)[i];
        ushort4 h, l; bf16split4(f, h, l);
        ((ushort4*)hi)[i] = h; ((ushort4*)lo)[i] = l;
    }
}

// ============================================================
// Prep 2: transpose + split.  W:[512][ncols] fp32 -> out:[ncols][512] hi/lo
// ============================================================
__global__ __launch_bounds__(256) void tsplit_kernel(
    const float* __restrict__ W, int ncols, u16* __restrict__ ohi, u16* __restrict__ olo)
{
    __shared__ float t_s[64][65];
    const int tid = threadIdx.x, tx = tid & 15, ty = tid >> 4;
    const int cb = blockIdx.x * 64, kb = blockIdx.y * 64;
    #pragma unroll
    for (int i = 0; i < 4; i++)
        *(float4*)&t_s[ty*4+i][tx*4] =
            *(const float4*)(W + (size_t)(kb + ty*4 + i) * ncols + cb + tx*4);
    __syncthreads();
    #pragma unroll
    for (int i = 0; i < 4; i++) {
        int rr = ty*4 + i;
        float4 f;
        f.x = t_s[tx*4+0][rr]; f.y = t_s[tx*4+1][rr];
        f.z = t_s[tx*4+2][rr]; f.w = t_s[tx*4+3][rr];
        ushort4 h, l; bf16split4(f, h, l);
        *(ushort4*)(ohi + (size_t)(cb + rr) * 512 + kb + tx*4) = h;
        *(ushort4*)(olo + (size_t)(cb + rr) * 512 + kb + tx*4) = l;
    }
}

// ============================================================
// Kernel 1: QKV projection, split-bf16 MFMA.
// Epilogue: bias; q: relu then *0.125 (exact pow2 — pre-scales scores);
// q,k -> bf16 hi/lo planes, v fp32.
// ============================================================
__global__ __launch_bounds__(256) void qkv_mfma_kernel(
    const u16* __restrict__ xpl,      // [2][8192][512]
    const u16* __restrict__ wtpl,     // [2][1536][512]
    const float* __restrict__ bq, const float* __restrict__ bkv,
    u16* __restrict__ qhi_g, u16* __restrict__ qlo_g,
    u16* __restrict__ khi_g, u16* __restrict__ klo_g,
    float* __restrict__ v_ws)
{
    __shared__ __align__(16) char smem[32768];
    u16*   a_s = (u16*)smem;              // [2][4096] shorts
    u16*   b_s = (u16*)(smem + 16384);    // [2][4096] shorts
    float* e_s = (float*)smem;            // epilogue overlay [32][132]

    const int tid = threadIdx.x, lane = tid & 63, w = tid >> 6;
    const int row0 = blockIdx.x * 128;
    const int by = blockIdx.y;            // 0..11: 0-3 q, 4-7 k, 8-11 v
    const int c0 = by * 128;

    f32x4v acc[2][8];
    #pragma unroll
    for (int rt = 0; rt < 2; rt++)
        #pragma unroll
        for (int nt = 0; nt < 8; nt++) acc[rt][nt] = (f32x4v){0.f,0.f,0.f,0.f};

    int gpl[4], goff_a[4], goff_b[4], glds[4];
    #pragma unroll
    for (int i = 0; i < 4; i++) {
        int gid = tid * 4 + i;
        int pl = gid >> 9, rem = gid & 511;
        int rt = rem >> 6, l = rem & 63;
        gpl[i]    = pl;
        goff_a[i] = (row0 + rt*16 + (l & 15)) * 512 + ((l >> 4) * 8);
        goff_b[i] = (c0   + rt*16 + (l & 15)) * 512 + ((l >> 4) * 8);
        glds[i]   = pl * 4096 + (rt*64 + l) * 8;
    }

    uint4 ar[4], br[4];
    #pragma unroll
    for (int i = 0; i < 4; i++) {
        ar[i] = *(const uint4*)(xpl  + (size_t)gpl[i]*XPLANE  + goff_a[i]);
        br[i] = *(const uint4*)(wtpl + (size_t)gpl[i]*WTPLANE + goff_b[i]);
    }

    for (int kc = 0; kc < 16; kc++) {
        __syncthreads();
        #pragma unroll
        for (int i = 0; i < 4; i++) {
            *(uint4*)&a_s[glds[i]] = ar[i];
            *(uint4*)&b_s[glds[i]] = br[i];
        }
        __syncthreads();
        if (kc < 15) {
            int ko = (kc + 1) * 32;
            #pragma unroll
            for (int i = 0; i < 4; i++) {
                ar[i] = *(const uint4*)(xpl  + (size_t)gpl[i]*XPLANE  + goff_a[i] + ko);
                br[i] = *(const uint4*)(wtpl + (size_t)gpl[i]*WTPLANE + goff_b[i] + ko);
            }
        }
        bf16x8 a0h = *(bf16x8*)&a_s[(((2*w+0)*64) + lane) * 8];
        bf16x8 a0l = *(bf16x8*)&a_s[4096 + (((2*w+0)*64) + lane) * 8];
        bf16x8 a1h = *(bf16x8*)&a_s[(((2*w+1)*64) + lane) * 8];
        bf16x8 a1l = *(bf16x8*)&a_s[4096 + (((2*w+1)*64) + lane) * 8];
        #pragma unroll
        for (int nt = 0; nt < 8; nt++) {
            bf16x8 bh_ = *(bf16x8*)&b_s[(nt*64 + lane) * 8];
            bf16x8 bl_ = *(bf16x8*)&b_s[4096 + (nt*64 + lane) * 8];
            acc[0][nt] = MFMA16(a0h, bh_, acc[0][nt]);
            acc[0][nt] = MFMA16(a0h, bl_, acc[0][nt]);
            acc[0][nt] = MFMA16(a0l, bh_, acc[0][nt]);
            acc[1][nt] = MFMA16(a1h, bh_, acc[1][nt]);
            acc[1][nt] = MFMA16(a1h, bl_, acc[1][nt]);
            acc[1][nt] = MFMA16(a1l, bh_, acc[1][nt]);
        }
    }

    for (int p = 0; p < 4; p++) {
        __syncthreads();
        if (w == p) {
            #pragma unroll
            for (int rt = 0; rt < 2; rt++)
                #pragma unroll
                for (int nt = 0; nt < 8; nt++) {
                    int rl = rt*16 + (lane >> 4) * 4;
                    int cl = nt*16 + (lane & 15);
                    #pragma unroll
                    for (int rg = 0; rg < 4; rg++)
                        e_s[(rl + rg) * 132 + cl] = acc[rt][nt][rg];
                }
        }
        __syncthreads();
        int rl = tid >> 3;                // 0..31
        int cb = (tid & 7) * 16;
        int rg = row0 + p*32 + rl;
        int bb = rg >> 10, nn = rg & (SEQ - 1);
        #pragma unroll
        for (int j4 = 0; j4 < 4; j4++) {
            float4 f = *(float4*)&e_s[rl * 132 + cb + j4*4];
            int cg = c0 + cb + j4*4;      // 0..1535
            if (by < 4) {
                float4 bias = *(const float4*)(bq + cg);
                f.x = fmaxf(f.x + bias.x, 0.f) * 0.125f;
                f.y = fmaxf(f.y + bias.y, 0.f) * 0.125f;
                f.z = fmaxf(f.z + bias.z, 0.f) * 0.125f;
                f.w = fmaxf(f.w + bias.w, 0.f) * 0.125f;
                int h = cg >> 6, d = cg & 63;
                size_t base = (((size_t)bb*HEADS + h)*SEQ + nn)*HD + d;
                ushort4 hv, lv; bf16split4(f, hv, lv);
                *(ushort4*)(qhi_g + base) = hv;
                *(ushort4*)(qlo_g + base) = lv;
            } else {
                int c2 = cg - CDIM;       // 0..1023
                float4 bias = *(const float4*)(bkv + c2);
                f.x += bias.x; f.y += bias.y; f.z += bias.z; f.w += bias.w;
                if (by < 8) {             // k
                    int h = c2 >> 6, d = c2 & 63;
                    size_t base = (((size_t)bb*HEADS + h)*SEQ + nn)*HD + d;
                    ushort4 hv, lv; bf16split4(f, hv, lv);
                    *(ushort4*)(khi_g + base) = hv;
                    *(ushort4*)(klo_g + base) = lv;
                } else {                  // v
                    int c3 = c2 - CDIM; int h = c3 >> 6, d = c3 & 63;
                    size_t base = (((size_t)bb*HEADS + h)*SEQ + nn)*HD + d;
                    *(float4*)(v_ws + base) = f;
                }
            }
        }
    }
}

// ============================================================
// Kernel 2: per-(b,h) column sum of V  -> vsum[bh][64]
// ============================================================
__global__ __launch_bounds__(256) void vsum_kernel(
    const float* __restrict__ v_ws, float* __restrict__ vsum_ws)
{
    __shared__ float red[4][HD];
    const int bh = blockIdx.x;
    const int d  = threadIdx.x & 63;
    const int sl = threadIdx.x >> 6;
    const float* vh = v_ws + (size_t)bh * SEQ * HD;
    float s = 0.f;
    for (int m = sl * 256; m < (sl + 1) * 256; m++) s += vh[(size_t)m * HD + d];
    red[sl][d] = s;
    __syncthreads();
    if (threadIdx.x < HD)
        vsum_ws[(size_t)bh * HD + d] = red[0][d] + red[1][d] + red[2][d] + red[3][d];
}

// ============================================================
// Kernel 3a: scores -> global fp32 [bhl][row][col], row-major.
// Zero LDS, zero barriers. Block = (row-block nb, col-quarter cb):
// 64 rows x 256 cols. Q/K fragments direct from the global hi/lo
// planes (fragment-contiguous 16B per lane). Pure load->MFMA->store.
// q already carries the 0.125 scale.
// ============================================================
__global__ __launch_bounds__(256) void score_kernel(
    const u16* __restrict__ qhi_g, const u16* __restrict__ qlo_g,
    const u16* __restrict__ khi_g, const u16* __restrict__ klo_g,
    float* __restrict__ s_g, int bh0)
{
    const int bhl = blockIdx.y, bh = bh0 + bhl;
    const int nb = blockIdx.x & 15, cb = blockIdx.x >> 4;
    const int tid = threadIdx.x, lane = tid & 63, w = tid >> 6;
    const int n0 = nb * 64 + w * 16;              // wave's first row
    const size_t hb = (size_t)bh * SEQ * HD;
    const int l15 = lane & 15, l4 = lane >> 4;

    // Q fragments: A[m = n0+l15][k = l4*8 + h*32]
    bf16x8 qh[2], ql[2];
    {
        const size_t qoff = hb + (size_t)(n0 + l15) * HD + l4 * 8;
        qh[0] = *(const bf16x8*)(qhi_g + qoff);
        qh[1] = *(const bf16x8*)(qhi_g + qoff + 32);
        ql[0] = *(const bf16x8*)(qlo_g + qoff);
        ql[1] = *(const bf16x8*)(qlo_g + qoff + 32);
    }

    float* sbase = s_g + ((size_t)bhl << 20);
    const int rowb = n0 + l4 * 4;                 // C-layout row base

    #pragma unroll 2
    for (int T = 0; T < 16; T++) {
        const int col16 = cb * 256 + T * 16;
        const size_t koff = hb + (size_t)(col16 + l15) * HD + l4 * 8;
        bf16x8 kh0 = *(const bf16x8*)(khi_g + koff);
        bf16x8 kh1 = *(const bf16x8*)(khi_g + koff + 32);
        bf16x8 kl0 = *(const bf16x8*)(klo_g + koff);
        bf16x8 kl1 = *(const bf16x8*)(klo_g + koff + 32);
        f32x4v acc = {0.f, 0.f, 0.f, 0.f};
        acc = MFMA16(qh[0], kh0, acc);
        acc = MFMA16(qh[0], kl0, acc);
        acc = MFMA16(ql[0], kh0, acc);
        acc = MFMA16(qh[1], kh1, acc);
        acc = MFMA16(qh[1], kl1, acc);
        acc = MFMA16(ql[1], kh1, acc);
        // C/D: col = col16 + l15, rows rowb..rowb+3
        float* sp = sbase + ((size_t)rowb << 10) + col16 + l15;
        sp[0 << 10] = acc[0];
        sp[1 << 10] = acc[1];
        sp[2 << 10] = acc[2];
        sp[3 << 10] = acc[3];
    }
}

// ============================================================
// Kernel 3b: per-row top-16 (exact jax tie order) + sparse softmax + PV.
// One wave per (bhl, n) row. Lane l holds score cols l*16..l*16+15
// (coalesced float4 loads); 16 rounds of wave argmax extraction
// (value desc, col asc). Output ao as bf16 hi/lo planes. Zero LDS.
// ============================================================
__global__ __launch_bounds__(256) void topk_pv_kernel(
    const float* __restrict__ s_g, const float* __restrict__ v_ws,
    const float* __restrict__ vsum_ws,
    u16* __restrict__ aohi, u16* __restrict__ aolo, int bh0)
{
    const int lane = threadIdx.x & 63;
    const int wid  = (blockIdx.x * 256 + threadIdx.x) >> 6;
    const int bhl  = wid >> 10;
    const int n    = wid & (SEQ - 1);
    const int bh   = bh0 + bhl;

    const float* srow = s_g + ((size_t)bhl << 20) + ((size_t)n << 10) + lane * 16;
    float v[16];
    #pragma unroll
    for (int i = 0; i < 4; i++) {
        float4 t = *(const float4*)(srow + i * 4);
        v[i*4+0] = t.x; v[i*4+1] = t.y; v[i*4+2] = t.z; v[i*4+3] = t.w;
    }

    float mv[TOPK]; int mi[TOPK];
    #pragma unroll
    for (int t = 0; t < TOPK; t++) {
        float bv = v[0]; int bj = 0;
        #pragma unroll
        for (int j = 1; j < 16; j++) { if (v[j] > bv) { bv = v[j]; bj = j; } }
        int bc = lane * 16 + bj;
        #pragma unroll
        for (int off = 32; off; off >>= 1) {
            float ov = __shfl_xor(bv, off);
            int   oc = __shfl_xor(bc, off);
            if (ov > bv || (ov == bv && oc < bc)) { bv = ov; bc = oc; }
        }
        mv[t] = bv; mi[t] = bc;
        int jj = bc - lane * 16;            // in [0,16) only for owner
        #pragma unroll
        for (int j = 0; j < 16; j++) { if (j == jj) v[j] = -FLT_MAX; }
    }

    float mx = fmaxf(mv[0], 0.f);
    float e  = expf(-mx);
    float Z  = (float)(SEQ - TOPK) * e;
    float wexp[TOPK];
    #pragma unroll
    for (int t = 0; t < TOPK; t++) { wexp[t] = expf(mv[t] - mx); Z += wexp[t]; }
    float invZ = 1.f / Z;

    const float* vh = v_ws + ((size_t)bh << 16);
    float acc = (e * invZ) * vsum_ws[(bh << 6) + lane];
    #pragma unroll
    for (int t = 0; t < TOPK; t++)
        acc = fmaf((wexp[t] - e) * invZ, vh[((size_t)mi[t] << 6) + lane], acc);

    u16 oh, ol; bf16split(acc, oh, ol);
    size_t oidx = (((size_t)(bh >> 3) << 10) + n) * CDIM + ((bh & 7) << 6) + lane;
    aohi[oidx] = oh; aolo[oidx] = ol;
}

// ============================================================
// Kernel 4: output projection, split-bf16 MFMA.  out = ao @ Wp + bp
// ============================================================
__global__ __launch_bounds__(256) void proj_mfma_kernel(
    const u16* __restrict__ apl,      // [2][8192][512]
    const u16* __restrict__ wppl,     // [2][512][512]
    const float* __restrict__ bp, float* __restrict__ out)
{
    __shared__ __align__(16) char smem[32768];
    u16*   a_s = (u16*)smem;
    u16*   b_s = (u16*)(smem + 16384);
    float* e_s = (float*)smem;

    const int tid = threadIdx.x, lane = tid & 63, w = tid >> 6;
    const int row0 = blockIdx.x * 128;
    const int c0 = blockIdx.y * 128;

    f32x4v acc[2][8];
    #pragma unroll
    for (int rt = 0; rt < 2; rt++)
        #pragma unroll
        for (int nt = 0; nt < 8; nt++) acc[rt][nt] = (f32x4v){0.f,0.f,0.f,0.f};

    int gpl[4], goff_a[4], goff_b[4], glds[4];
    #pragma unroll
    for (int i = 0; i < 4; i++) {
        int gid = tid * 4 + i;
        int pl = gid >> 9, rem = gid & 511;
        int rt = rem >> 6, l = rem & 63;
        gpl[i]    = pl;
        goff_a[i] = (row0 + rt*16 + (l & 15)) * 512 + ((l >> 4) * 8);
        goff_b[i] = (c0   + rt*16 + (l & 15)) * 512 + ((l >> 4) * 8);
        glds[i]   = pl * 4096 + (rt*64 + l) * 8;
    }

    uint4 ar[4], br[4];
    #pragma unroll
    for (int i = 0; i < 4; i++) {
        ar[i] = *(const uint4*)(apl  + (size_t)gpl[i]*XPLANE  + goff_a[i]);
        br[i] = *(const uint4*)(wppl + (size_t)gpl[i]*WPPLANE + goff_b[i]);
    }

    for (int kc = 0; kc < 16; kc++) {
        __syncthreads();
        #pragma unroll
        for (int i = 0; i < 4; i++) {
            *(uint4*)&a_s[glds[i]] = ar[i];
            *(uint4*)&b_s[glds[i]] = br[i];
        }
        __syncthreads();
        if (kc < 15) {
            int ko = (kc + 1) * 32;
            #pragma unroll
            for (int i = 0; i < 4; i++) {
                ar[i] = *(const uint4*)(apl  + (size_t)gpl[i]*XPLANE  + goff_a[i] + ko);
                br[i] = *(const uint4*)(wppl + (size_t)gpl[i]*WPPLANE + goff_b[i] + ko);
            }
        }
        bf16x8 a0h = *(bf16x8*)&a_s[(((2*w+0)*64) + lane) * 8];
        bf16x8 a0l = *(bf16x8*)&a_s[4096 + (((2*w+0)*64) + lane) * 8];
        bf16x8 a1h = *(bf16x8*)&a_s[(((2*w+1)*64) + lane) * 8];
        bf16x8 a1l = *(bf16x8*)&a_s[4096 + (((2*w+1)*64) + lane) * 8];
        #pragma unroll
        for (int nt = 0; nt < 8; nt++) {
            bf16x8 bh_ = *(bf16x8*)&b_s[(nt*64 + lane) * 8];
            bf16x8 bl_ = *(bf16x8*)&b_s[4096 + (nt*64 + lane) * 8];
            acc[0][nt] = MFMA16(a0h, bh_, acc[0][nt]);
            acc[0][nt] = MFMA16(a0h, bl_, acc[0][nt]);
            acc[0][nt] = MFMA16(a0l, bh_, acc[0][nt]);
            acc[1][nt] = MFMA16(a1h, bh_, acc[1][nt]);
            acc[1][nt] = MFMA16(a1h, bl_, acc[1][nt]);
            acc[1][nt] = MFMA16(a1l, bh_, acc[1][nt]);
        }
    }

    for (int p = 0; p < 4; p++) {
        __syncthreads();
        if (w == p) {
            #pragma unroll
            for (int rt = 0; rt < 2; rt++)
                #pragma unroll
                for (int nt = 0; nt < 8; nt++) {
                    int rl = rt*16 + (lane >> 4) * 4;
                    int cl = nt*16 + (lane & 15);
                    #pragma unroll
                    for (int rg = 0; rg < 4; rg++)
                        e_s[(rl + rg) * 132 + cl] = acc[rt][nt][rg];
                }
        }
        __syncthreads();
        int rl = tid >> 3;
        int cb = (tid & 7) * 16;
        int rg = row0 + p*32 + rl;
        #pragma unroll
        for (int j4 = 0; j4 < 4; j4++) {
            float4 f = *(float4*)&e_s[rl * 132 + cb + j4*4];
            int cg = c0 + cb + j4*4;
            float4 bias = *(const float4*)(bp + cg);
            f.x += bias.x; f.y += bias.y; f.z += bias.z; f.w += bias.w;
            *(float4*)(out + (size_t)rg * CDIM + cg) = f;
        }
    }
}

// ============================================================
extern "C" void kernel_launch(void* const* d_in, const int* in_sizes, int n_in,
                              void* d_out, int out_size, void* d_ws, size_t ws_size,
                              hipStream_t stream)
{
    const float* x   = (const float*)d_in[0];
    const float* Wq  = (const float*)d_in[1];
    const float* bq  = (const float*)d_in[2];
    const float* Wkv = (const float*)d_in[3];
    const float* bkv = (const float*)d_in[4];
    const float* Wp  = (const float*)d_in[5];
    const float* bp  = (const float*)d_in[6];
    float* out = (float*)d_out;

    // workspace layout
    float* ws    = (float*)d_ws;
    float* v_ws  = ws;                               // HSZ fl
    float* vs_ws = v_ws + HSZ;                       // 4096 fl
    u16* qhi_g = (u16*)(vs_ws + 4096);
    u16* qlo_g = qhi_g + HSZ;
    u16* khi_g = qhi_g + 2 * HSZ;
    u16* klo_g = qhi_g + 3 * HSZ;
    u16* xpl   = qhi_g + 4 * HSZ;                    // 2 planes
    u16* wtpl  = xpl + 2 * XPLANE;                   // 2 planes
    u16* wppl  = wtpl + 2 * WTPLANE;                 // 2 planes
    u16* aohi  = wppl + 2 * WPPLANE;
    u16* aolo  = aohi + XPLANE;
    float* s_g = (float*)(aolo + XPLANE);

    const size_t base_fl  = (size_t)(s_g - ws);
    const size_t avail_fl = (ws_size / 4 > base_fl) ? (ws_size / 4 - base_fl) : 0;
    int G = 64;
    while (G > 1 && (size_t)G * SEQ * SEQ > avail_fl) G >>= 1;

    split_f32_kernel<<<(int)((XPLANE/4 + 255)/256), 256, 0, stream>>>(
        x, xpl, xpl + XPLANE, (int)(XPLANE/4));
    tsplit_kernel<<<dim3(8, 8),  256, 0, stream>>>(Wq,  512,  wtpl, wtpl + WTPLANE);
    tsplit_kernel<<<dim3(16, 8), 256, 0, stream>>>(Wkv, 1024, wtpl + (size_t)512*512,
                                                   wtpl + WTPLANE + (size_t)512*512);
    tsplit_kernel<<<dim3(8, 8),  256, 0, stream>>>(Wp,  512,  wppl, wppl + WPPLANE);

    qkv_mfma_kernel<<<dim3(64, 12), 256, 0, stream>>>(
        xpl, wtpl, bq, bkv, qhi_g, qlo_g, khi_g, klo_g, v_ws);
    vsum_kernel<<<BATCH * HEADS, 256, 0, stream>>>(v_ws, vs_ws);
    for (int bh0 = 0; bh0 < BATCH * HEADS; bh0 += G) {
        score_kernel<<<dim3(64, G), 256, 0, stream>>>(
            qhi_g, qlo_g, khi_g, klo_g, s_g, bh0);
        topk_pv_kernel<<<dim3(G * (SEQ / 4)), 256, 0, stream>>>(
            s_g, v_ws, vs_ws, aohi, aolo, bh0);
    }
    proj_mfma_kernel<<<dim3(64, 4), 256, 0, stream>>>(aohi, wppl, bp, out);
}

// Round 8
// 593.479 us; speedup vs baseline: 1.5646x; 1.0810x over previous
//
#include <hip/hip_runtime.h>
#include <float.h>

#define BATCH 8
#define SEQ   1024
#define CDIM  512
#define HEADS 8
#define HD    64
#define TOPK  16
#define MTOT  (BATCH*SEQ)                     // 8192
#define HSZ   ((size_t)BATCH*HEADS*SEQ*HD)    // 4194304
#define XPLANE  ((size_t)MTOT*CDIM)           // 4194304
#define WTPLANE ((size_t)3*CDIM*CDIM)         // 786432  (1536x512)
#define WPPLANE ((size_t)CDIM*CDIM)           // 262144  (512x512)

typedef short bf16x8 __attribute__((ext_vector_type(8)));
typedef float f32x4v __attribute__((ext_vector_type(4)));
typedef unsigned short u16;

#define MFMA16(a,b,c) __builtin_amdgcn_mfma_f32_16x16x32_bf16((a),(b),(c),0,0,0)

// round-to-nearest bf16 split: f = hi + lo, each bf16; |err| ~ 2^-17 |f|
__device__ inline void bf16split(float f, u16& h, u16& l) {
    unsigned u = __float_as_uint(f);
    unsigned hr = (u + 0x7fffu + ((u >> 16) & 1u)) >> 16;
    h = (u16)hr;
    float rest = f - __uint_as_float(hr << 16);
    unsigned v = __float_as_uint(rest);
    l = (u16)((v + 0x7fffu + ((v >> 16) & 1u)) >> 16);
}

__device__ inline void bf16split4(float4 f, ushort4& h, ushort4& l) {
    bf16split(f.x, h.x, l.x); bf16split(f.y, h.y, l.y);
    bf16split(f.z, h.z, l.z); bf16split(f.w, h.w, l.w);
}

// ============================================================
// Prep 1: elementwise split fp32 -> bf16 hi/lo planes
// ============================================================
__global__ __launch_bounds__(256) void split_f32_kernel(
    const float* __restrict__ in, u16* __restrict__ hi, u16* __restrict__ lo, int n4)
{
    int i = blockIdx.x * 256 + threadIdx.x;
    if (i < n4) {
        float4 f = ((const float4*)in)[i];
        ushort4 h, l; bf16split4(f, h, l);
        ((ushort4*)hi)[i] = h; ((ushort4*)lo)[i] = l;
    }
}

// ============================================================
// Prep 2: transpose + split.  W:[512][ncols] fp32 -> out:[ncols][512] hi/lo
// ============================================================
__global__ __launch_bounds__(256) void tsplit_kernel(
    const float* __restrict__ W, int ncols, u16* __restrict__ ohi, u16* __restrict__ olo)
{
    __shared__ float t_s[64][65];
    const int tid = threadIdx.x, tx = tid & 15, ty = tid >> 4;
    const int cb = blockIdx.x * 64, kb = blockIdx.y * 64;
    #pragma unroll
    for (int i = 0; i < 4; i++)
        *(float4*)&t_s[ty*4+i][tx*4] =
            *(const float4*)(W + (size_t)(kb + ty*4 + i) * ncols + cb + tx*4);
    __syncthreads();
    #pragma unroll
    for (int i = 0; i < 4; i++) {
        int rr = ty*4 + i;
        float4 f;
        f.x = t_s[tx*4+0][rr]; f.y = t_s[tx*4+1][rr];
        f.z = t_s[tx*4+2][rr]; f.w = t_s[tx*4+3][rr];
        ushort4 h, l; bf16split4(f, h, l);
        *(ushort4*)(ohi + (size_t)(cb + rr) * 512 + kb + tx*4) = h;
        *(ushort4*)(olo + (size_t)(cb + rr) * 512 + kb + tx*4) = l;
    }
}

// ============================================================
// Kernel 1: QKV projection, split-bf16 MFMA, ZERO LDS / ZERO barriers.
// Wave owns 32 rows x 128 cols. Fragments loaded directly from global
// planes (16 complete 64B lines per load instruction). Grid (64,12):
// all 12 col-tiles of one row-block land on one XCD (linear ids differ
// by 64 = 0 mod 8) so A re-reads are L2-hits.
// Epilogue: bias; q: relu * 0.125 (pre-scales scores); scalar stores
// straight from acc (C layout: row = l4*4+rg (+rt*16), col = nt*16+l15).
// ============================================================
__global__ __launch_bounds__(256) void qkv_mfma_kernel(
    const u16* __restrict__ xpl,      // [2][8192][512]
    const u16* __restrict__ wtpl,     // [2][1536][512]
    const float* __restrict__ bq, const float* __restrict__ bkv,
    u16* __restrict__ qhi_g, u16* __restrict__ qlo_g,
    u16* __restrict__ khi_g, u16* __restrict__ klo_g,
    float* __restrict__ v_ws)
{
    const int tid = threadIdx.x, lane = tid & 63, w = tid >> 6;
    const int l15 = lane & 15, l4 = lane >> 4;
    const int row0 = blockIdx.x * 128 + w * 32;
    const int by = blockIdx.y;            // 0..11: 0-3 q, 4-7 k, 8-11 v
    const int c0 = by * 128;

    f32x4v acc[2][8];
    #pragma unroll
    for (int rt = 0; rt < 2; rt++)
        #pragma unroll
        for (int nt = 0; nt < 8; nt++) acc[rt][nt] = (f32x4v){0.f,0.f,0.f,0.f};

    const u16* aph = xpl  + (size_t)(row0 + l15) * 512 + l4 * 8;
    const u16* bph = wtpl + (size_t)(c0   + l15) * 512 + l4 * 8;

    #pragma unroll 2
    for (int kc = 0; kc < 16; kc++) {
        const int ko = kc * 32;
        bf16x8 a0h = *(const bf16x8*)(aph + ko);
        bf16x8 a0l = *(const bf16x8*)(aph + XPLANE + ko);
        bf16x8 a1h = *(const bf16x8*)(aph + 16*512 + ko);
        bf16x8 a1l = *(const bf16x8*)(aph + XPLANE + 16*512 + ko);
        #pragma unroll
        for (int nt = 0; nt < 8; nt++) {
            bf16x8 bh_ = *(const bf16x8*)(bph + nt*16*512 + ko);
            bf16x8 bl_ = *(const bf16x8*)(bph + WTPLANE + nt*16*512 + ko);
            acc[0][nt] = MFMA16(a0h, bh_, acc[0][nt]);
            acc[0][nt] = MFMA16(a0h, bl_, acc[0][nt]);
            acc[0][nt] = MFMA16(a0l, bh_, acc[0][nt]);
            acc[1][nt] = MFMA16(a1h, bh_, acc[1][nt]);
            acc[1][nt] = MFMA16(a1h, bl_, acc[1][nt]);
            acc[1][nt] = MFMA16(a1l, bh_, acc[1][nt]);
        }
    }

    // epilogue straight from acc; row = row0 + rt*16 + l4*4 + rg
    const int rbase = row0 + l4 * 4;
    if (by < 4) {
        #pragma unroll
        for (int nt = 0; nt < 8; nt++) {
            const int cg = c0 + nt*16 + l15;         // 0..511
            const int h = cg >> 6, d = cg & 63;
            const float bias = bq[cg];
            #pragma unroll
            for (int rt = 0; rt < 2; rt++)
                #pragma unroll
                for (int rg = 0; rg < 4; rg++) {
                    int r = rbase + rt*16 + rg;
                    int bb = r >> 10, nn = r & (SEQ - 1);
                    float f = fmaxf(acc[rt][nt][rg] + bias, 0.f) * 0.125f;
                    u16 hh, ll; bf16split(f, hh, ll);
                    size_t base = (((size_t)(bb*HEADS + h)) << 16) + ((size_t)nn << 6) + d;
                    qhi_g[base] = hh; qlo_g[base] = ll;
                }
        }
    } else if (by < 8) {
        #pragma unroll
        for (int nt = 0; nt < 8; nt++) {
            const int c2 = c0 - CDIM + nt*16 + l15;  // 0..511
            const int h = c2 >> 6, d = c2 & 63;
            const float bias = bkv[c2];
            #pragma unroll
            for (int rt = 0; rt < 2; rt++)
                #pragma unroll
                for (int rg = 0; rg < 4; rg++) {
                    int r = rbase + rt*16 + rg;
                    int bb = r >> 10, nn = r & (SEQ - 1);
                    float f = acc[rt][nt][rg] + bias;
                    u16 hh, ll; bf16split(f, hh, ll);
                    size_t base = (((size_t)(bb*HEADS + h)) << 16) + ((size_t)nn << 6) + d;
                    khi_g[base] = hh; klo_g[base] = ll;
                }
        }
    } else {
        #pragma unroll
        for (int nt = 0; nt < 8; nt++) {
            const int c3 = c0 - 2*CDIM + nt*16 + l15; // 0..511
            const int h = c3 >> 6, d = c3 & 63;
            const float bias = bkv[CDIM + c3];
            #pragma unroll
            for (int rt = 0; rt < 2; rt++)
                #pragma unroll
                for (int rg = 0; rg < 4; rg++) {
                    int r = rbase + rt*16 + rg;
                    int bb = r >> 10, nn = r & (SEQ - 1);
                    size_t base = (((size_t)(bb*HEADS + h)) << 16) + ((size_t)nn << 6) + d;
                    v_ws[base] = acc[rt][nt][rg] + bias;
                }
        }
    }
}

// ============================================================
// Kernel 2: V column sums, two stages for parallelism.
// ============================================================
__global__ __launch_bounds__(256) void vsum1_kernel(
    const float* __restrict__ v_ws, float* __restrict__ part)
{
    __shared__ float red[4][HD];
    const int bh = blockIdx.x, sl = blockIdx.y;
    const int d = threadIdx.x & 63, sub = threadIdx.x >> 6;
    const float* vh = v_ws + ((size_t)bh << 16) + ((size_t)(sl*128 + sub*32) << 6);
    float s = 0.f;
    #pragma unroll 4
    for (int m = 0; m < 32; m++) s += vh[(m << 6) + d];
    red[sub][d] = s;
    __syncthreads();
    if (threadIdx.x < HD)
        part[((size_t)bh*8 + sl)*HD + d] = red[0][d]+red[1][d]+red[2][d]+red[3][d];
}

__global__ __launch_bounds__(256) void vsum2_kernel(
    const float* __restrict__ part, float* __restrict__ vs)
{
    const int bh = blockIdx.x*4 + (threadIdx.x >> 6), d = threadIdx.x & 63;
    float s = 0.f;
    #pragma unroll
    for (int i = 0; i < 8; i++) s += part[((size_t)bh*8 + i)*HD + d];
    vs[(bh << 6) + d] = s;
}

// ============================================================
// Kernel 3a: scores -> global fp32 [bhl][row][col], row-major.
// Zero LDS, zero barriers. Block = (row-block nb, col-quarter cb):
// 64 rows x 256 cols. q pre-scaled by 0.125.
// ============================================================
__global__ __launch_bounds__(256) void score_kernel(
    const u16* __restrict__ qhi_g, const u16* __restrict__ qlo_g,
    const u16* __restrict__ khi_g, const u16* __restrict__ klo_g,
    float* __restrict__ s_g, int bh0)
{
    const int bhl = blockIdx.y, bh = bh0 + bhl;
    const int nb = blockIdx.x & 15, cb = blockIdx.x >> 4;
    const int tid = threadIdx.x, lane = tid & 63, w = tid >> 6;
    const int n0 = nb * 64 + w * 16;              // wave's first row
    const size_t hb = (size_t)bh * SEQ * HD;
    const int l15 = lane & 15, l4 = lane >> 4;

    bf16x8 qh[2], ql[2];
    {
        const size_t qoff = hb + (size_t)(n0 + l15) * HD + l4 * 8;
        qh[0] = *(const bf16x8*)(qhi_g + qoff);
        qh[1] = *(const bf16x8*)(qhi_g + qoff + 32);
        ql[0] = *(const bf16x8*)(qlo_g + qoff);
        ql[1] = *(const bf16x8*)(qlo_g + qoff + 32);
    }

    float* sbase = s_g + ((size_t)bhl << 20);
    const int rowb = n0 + l4 * 4;                 // C-layout row base

    #pragma unroll 2
    for (int T = 0; T < 16; T++) {
        const int col16 = cb * 256 + T * 16;
        const size_t koff = hb + (size_t)(col16 + l15) * HD + l4 * 8;
        bf16x8 kh0 = *(const bf16x8*)(khi_g + koff);
        bf16x8 kh1 = *(const bf16x8*)(khi_g + koff + 32);
        bf16x8 kl0 = *(const bf16x8*)(klo_g + koff);
        bf16x8 kl1 = *(const bf16x8*)(klo_g + koff + 32);
        f32x4v acc = {0.f, 0.f, 0.f, 0.f};
        acc = MFMA16(qh[0], kh0, acc);
        acc = MFMA16(qh[0], kl0, acc);
        acc = MFMA16(ql[0], kh0, acc);
        acc = MFMA16(qh[1], kh1, acc);
        acc = MFMA16(qh[1], kl1, acc);
        acc = MFMA16(ql[1], kh1, acc);
        float* sp = sbase + ((size_t)rowb << 10) + col16 + l15;
        sp[0 << 10] = acc[0];
        sp[1 << 10] = acc[1];
        sp[2 << 10] = acc[2];
        sp[3 << 10] = acc[3];
    }
}

// ============================================================
// Kernel 3b: per-row top-16 (exact jax tie order) + sparse softmax + PV.
// One wave per (bhl, n) row; 16 rounds of wave argmax extraction
// (value desc, col asc). Output ao as bf16 hi/lo planes. Zero LDS.
// ============================================================
__global__ __launch_bounds__(256) void topk_pv_kernel(
    const float* __restrict__ s_g, const float* __restrict__ v_ws,
    const float* __restrict__ vsum_ws,
    u16* __restrict__ aohi, u16* __restrict__ aolo, int bh0)
{
    const int lane = threadIdx.x & 63;
    const int wid  = (blockIdx.x * 256 + threadIdx.x) >> 6;
    const int bhl  = wid >> 10;
    const int n    = wid & (SEQ - 1);
    const int bh   = bh0 + bhl;

    const float* srow = s_g + ((size_t)bhl << 20) + ((size_t)n << 10) + lane * 16;
    float v[16];
    #pragma unroll
    for (int i = 0; i < 4; i++) {
        float4 t = *(const float4*)(srow + i * 4);
        v[i*4+0] = t.x; v[i*4+1] = t.y; v[i*4+2] = t.z; v[i*4+3] = t.w;
    }

    float mv[TOPK]; int mi[TOPK];
    #pragma unroll
    for (int t = 0; t < TOPK; t++) {
        float bv = v[0]; int bj = 0;
        #pragma unroll
        for (int j = 1; j < 16; j++) { if (v[j] > bv) { bv = v[j]; bj = j; } }
        int bc = lane * 16 + bj;
        #pragma unroll
        for (int off = 32; off; off >>= 1) {
            float ov = __shfl_xor(bv, off);
            int   oc = __shfl_xor(bc, off);
            if (ov > bv || (ov == bv && oc < bc)) { bv = ov; bc = oc; }
        }
        mv[t] = bv; mi[t] = bc;
        int jj = bc - lane * 16;            // in [0,16) only for owner
        #pragma unroll
        for (int j = 0; j < 16; j++) { if (j == jj) v[j] = -FLT_MAX; }
    }

    float mx = fmaxf(mv[0], 0.f);
    float e  = expf(-mx);
    float Z  = (float)(SEQ - TOPK) * e;
    float wexp[TOPK];
    #pragma unroll
    for (int t = 0; t < TOPK; t++) { wexp[t] = expf(mv[t] - mx); Z += wexp[t]; }
    float invZ = 1.f / Z;

    const float* vh = v_ws + ((size_t)bh << 16);
    float acc = (e * invZ) * vsum_ws[(bh << 6) + lane];
    #pragma unroll
    for (int t = 0; t < TOPK; t++)
        acc = fmaf((wexp[t] - e) * invZ, vh[((size_t)mi[t] << 6) + lane], acc);

    u16 oh, ol; bf16split(acc, oh, ol);
    size_t oidx = (((size_t)(bh >> 3) << 10) + n) * CDIM + ((bh & 7) << 6) + lane;
    aohi[oidx] = oh; aolo[oidx] = ol;
}

// ============================================================
// Kernel 4: output projection, split-bf16 MFMA, ZERO LDS / barriers.
// Wave owns 32 rows x 64 cols. Grid (128, 4) -> 512 blocks, 2/CU.
// ============================================================
__global__ __launch_bounds__(256) void proj_mfma_kernel(
    const u16* __restrict__ apl,      // [2][8192][512]
    const u16* __restrict__ wppl,     // [2][512][512]
    const float* __restrict__ bp, float* __restrict__ out)
{
    const int tid = threadIdx.x, lane = tid & 63, w = tid >> 6;
    const int l15 = lane & 15, l4 = lane >> 4;
    const int row0 = blockIdx.x * 64 + (w >> 1) * 32;
    const int c0   = blockIdx.y * 128 + (w & 1) * 64;

    f32x4v acc[2][4];
    #pragma unroll
    for (int rt = 0; rt < 2; rt++)
        #pragma unroll
        for (int nt = 0; nt < 4; nt++) acc[rt][nt] = (f32x4v){0.f,0.f,0.f,0.f};

    const u16* aph = apl  + (size_t)(row0 + l15) * 512 + l4 * 8;
    const u16* bph = wppl + (size_t)(c0   + l15) * 512 + l4 * 8;

    #pragma unroll 2
    for (int kc = 0; kc < 16; kc++) {
        const int ko = kc * 32;
        bf16x8 a0h = *(const bf16x8*)(aph + ko);
        bf16x8 a0l = *(const bf16x8*)(aph + XPLANE + ko);
        bf16x8 a1h = *(const bf16x8*)(aph + 16*512 + ko);
        bf16x8 a1l = *(const bf16x8*)(aph + XPLANE + 16*512 + ko);
        #pragma unroll
        for (int nt = 0; nt < 4; nt++) {
            bf16x8 bh_ = *(const bf16x8*)(bph + nt*16*512 + ko);
            bf16x8 bl_ = *(const bf16x8*)(bph + WPPLANE + nt*16*512 + ko);
            acc[0][nt] = MFMA16(a0h, bh_, acc[0][nt]);
            acc[0][nt] = MFMA16(a0h, bl_, acc[0][nt]);
            acc[0][nt] = MFMA16(a0l, bh_, acc[0][nt]);
            acc[1][nt] = MFMA16(a1h, bh_, acc[1][nt]);
            acc[1][nt] = MFMA16(a1h, bl_, acc[1][nt]);
            acc[1][nt] = MFMA16(a1l, bh_, acc[1][nt]);
        }
    }

    const int rbase = row0 + l4 * 4;
    #pragma unroll
    for (int nt = 0; nt < 4; nt++) {
        const int cg = c0 + nt*16 + l15;
        const float bias = bp[cg];
        #pragma unroll
        for (int rt = 0; rt < 2; rt++)
            #pragma unroll
            for (int rg = 0; rg < 4; rg++) {
                int r = rbase + rt*16 + rg;
                out[(size_t)r * CDIM + cg] = acc[rt][nt][rg] + bias;
            }
    }
}

// ============================================================
extern "C" void kernel_launch(void* const* d_in, const int* in_sizes, int n_in,
                              void* d_out, int out_size, void* d_ws, size_t ws_size,
                              hipStream_t stream)
{
    const float* x   = (const float*)d_in[0];
    const float* Wq  = (const float*)d_in[1];
    const float* bq  = (const float*)d_in[2];
    const float* Wkv = (const float*)d_in[3];
    const float* bkv = (const float*)d_in[4];
    const float* Wp  = (const float*)d_in[5];
    const float* bp  = (const float*)d_in[6];
    float* out = (float*)d_out;

    // workspace layout
    float* ws    = (float*)d_ws;
    float* v_ws  = ws;                               // HSZ fl
    float* vs_ws = v_ws + HSZ;                       // 4096 fl
    float* vp_ws = vs_ws + 4096;                     // 32768 fl (vsum partials)
    u16* qhi_g = (u16*)(vp_ws + 32768);
    u16* qlo_g = qhi_g + HSZ;
    u16* khi_g = qhi_g + 2 * HSZ;
    u16* klo_g = qhi_g + 3 * HSZ;
    u16* xpl   = qhi_g + 4 * HSZ;                    // 2 planes
    u16* wtpl  = xpl + 2 * XPLANE;                   // 2 planes
    u16* wppl  = wtpl + 2 * WTPLANE;                 // 2 planes
    u16* aohi  = wppl + 2 * WPPLANE;
    u16* aolo  = aohi + XPLANE;
    float* s_g = (float*)(aolo + XPLANE);

    const size_t base_fl  = (size_t)(s_g - ws);
    const size_t avail_fl = (ws_size / 4 > base_fl) ? (ws_size / 4 - base_fl) : 0;
    int G = 64;
    while (G > 1 && (size_t)G * SEQ * SEQ > avail_fl) G >>= 1;

    split_f32_kernel<<<(int)((XPLANE/4 + 255)/256), 256, 0, stream>>>(
        x, xpl, xpl + XPLANE, (int)(XPLANE/4));
    tsplit_kernel<<<dim3(8, 8),  256, 0, stream>>>(Wq,  512,  wtpl, wtpl + WTPLANE);
    tsplit_kernel<<<dim3(16, 8), 256, 0, stream>>>(Wkv, 1024, wtpl + (size_t)512*512,
                                                   wtpl + WTPLANE + (size_t)512*512);
    tsplit_kernel<<<dim3(8, 8),  256, 0, stream>>>(Wp,  512,  wppl, wppl + WPPLANE);

    qkv_mfma_kernel<<<dim3(64, 12), 256, 0, stream>>>(
        xpl, wtpl, bq, bkv, qhi_g, qlo_g, khi_g, klo_g, v_ws);
    vsum1_kernel<<<dim3(BATCH * HEADS, 8), 256, 0, stream>>>(v_ws, vp_ws);
    vsum2_kernel<<<16, 256, 0, stream>>>(vp_ws, vs_ws);
    for (int bh0 = 0; bh0 < BATCH * HEADS; bh0 += G) {
        score_kernel<<<dim3(64, G), 256, 0, stream>>>(
            qhi_g, qlo_g, khi_g, klo_g, s_g, bh0);
        topk_pv_kernel<<<dim3(G * (SEQ / 4)), 256, 0, stream>>>(
            s_g, v_ws, vs_ws, aohi, aolo, bh0);
    }
    proj_mfma_kernel<<<dim3(128, 4), 256, 0, stream>>>(aohi, wppl, bp, out);
}